// Round 5
// baseline (46.887 us; speedup 1.0000x reference)
//
#include <hip/hip_runtime.h>
#include <hip/hip_bf16.h>
#include <math.h>

// out[i,j] = max( (x[i]·W[j]) / (|x_i| |W_j|), 1e-10 ) + b[j]
// B=65536, IN=OUT=256, fp32 in/out.
// Round 5: R4 structure + (a) depth-4 register ring prefetch of x (loads lead
// use by ~1400 cyc > 900 cyc HBM latency), (b) epilogue stores are REGULAR
// (write-back, L2-merged) with sequential lane mapping; swizzle is undone on
// the LDS read address instead of the store address.

using bf16x8 = __attribute__((ext_vector_type(8))) short;   // 8 bf16 = 4 VGPRs
using f32x4  = __attribute__((ext_vector_type(4))) float;

#define W_LDS_BYTES 131072                        // 256 rows * 512 B (bf16, swizzled)
#define LDS_BYTES   (W_LDS_BYTES + 1024 + 1024)   // + winv[256] + b[256]
#define EPS 1e-10f

__device__ __forceinline__ short f2bf(float f) {
    __bf16 h = (__bf16)f;                         // RNE; pairs fuse to v_cvt_pk_bf16_f32
    return __builtin_bit_cast(short, h);
}

__global__ __launch_bounds__(1024, 4) void ffn_cosnorm_kernel(
    const float* __restrict__ x, const float* __restrict__ W,
    const float* __restrict__ b, float* __restrict__ out)
{
    extern __shared__ char smem[];
    float* winv = (float*)(smem + W_LDS_BYTES);           // [256] 1/|W_j|
    float* blds = (float*)(smem + W_LDS_BYTES + 1024);    // [256] bias

    const int t    = threadIdx.x;
    const int lane = t & 63;
    const int wave = t >> 6;                  // 0..15
    const int r16  = lane & 15;               // x row within wave's 16-row tile
    const int kg   = lane >> 4;               // 0..3 : K-slice of 8
    const int r7   = r16 & 7;
    const size_t rowb = (size_t)blockIdx.x * 256 + (size_t)wave * 16;
    const float* xp = x + (rowb + r16) * 256 + kg * 8;

    // ---- pre-issue 4 K-steps of x: land during the W prologue; ring depth 4 ----
    float4 ra[4], rb[4];
    #pragma unroll
    for (int s = 0; s < 4; ++s) {
        ra[s] = *(const float4*)(xp + s * 32);
        rb[s] = *(const float4*)(xp + s * 32 + 4);
    }

    // ---------------- prologue: stage W (fp32->bf16, XOR-swizzled) + w_len ----------------
    {
        const int wrow = t >> 2;              // 0..255 W row (output col j)
        const int q    = t & 3;               // 64-float quarter of the row
        const float* wr = W + (size_t)wrow * 256 + q * 64;
        const int rx = (wrow & 7) << 4;       // swizzle term
        float ss = 0.f;
        #pragma unroll
        for (int i = 0; i < 8; ++i) {         // 8 groups of 8 floats
            float4 a = *(const float4*)(wr + i * 8);
            float4 c = *(const float4*)(wr + i * 8 + 4);
            ss = fmaf(a.x, a.x, ss); ss = fmaf(a.y, a.y, ss);
            ss = fmaf(a.z, a.z, ss); ss = fmaf(a.w, a.w, ss);
            ss = fmaf(c.x, c.x, ss); ss = fmaf(c.y, c.y, ss);
            ss = fmaf(c.z, c.z, ss); ss = fmaf(c.w, c.w, ss);
            bf16x8 v;
            v[0] = f2bf(a.x); v[1] = f2bf(a.y); v[2] = f2bf(a.z); v[3] = f2bf(a.w);
            v[4] = f2bf(c.x); v[5] = f2bf(c.y); v[6] = f2bf(c.z); v[7] = f2bf(c.w);
            const int off = wrow * 512 + ((q * 128 + i * 16) ^ rx);
            *(bf16x8*)(smem + off) = v;       // ds_write_b128
        }
        ss += __shfl_xor(ss, 1);              // combine the 4 quarters
        ss += __shfl_xor(ss, 2);
        if (q == 0) winv[wrow] = 1.0f / sqrtf(ss);
        if (t < 256) blds[t] = b[t];
    }
    __syncthreads();

    // ---------------- main: each wave one 16-row M-tile, all 256 cols ----------------
    const int rxor = r7 << 4;                 // W-frag read swizzle

    f32x4 acc[16];
    #pragma unroll
    for (int n = 0; n < 16; ++n) acc[n] = f32x4{0.f, 0.f, 0.f, 0.f};
    float ssx = 0.f;

    #pragma unroll
    for (int k0 = 0; k0 < 8; ++k0) {          // K = 8 steps of 32
        const int slot = k0 & 3;              // static after full unroll
        float4 ca = ra[slot], cb = rb[slot];
        if (k0 < 4) {                         // ring refill: 4 K-steps ahead
            const float* p = xp + (k0 + 4) * 32;
            ra[slot] = *(const float4*)(p);
            rb[slot] = *(const float4*)(p + 4);
        }
        bf16x8 a0;
        a0[0] = f2bf(ca.x); a0[1] = f2bf(ca.y); a0[2] = f2bf(ca.z); a0[3] = f2bf(ca.w);
        a0[4] = f2bf(cb.x); a0[5] = f2bf(cb.y); a0[6] = f2bf(cb.z); a0[7] = f2bf(cb.w);
        ssx = fmaf(ca.x, ca.x, ssx); ssx = fmaf(ca.y, ca.y, ssx);
        ssx = fmaf(ca.z, ca.z, ssx); ssx = fmaf(ca.w, ca.w, ssx);
        ssx = fmaf(cb.x, cb.x, ssx); ssx = fmaf(cb.y, cb.y, ssx);
        ssx = fmaf(cb.z, cb.z, ssx); ssx = fmaf(cb.w, cb.w, ssx);

        const int cswz = (k0 * 64 + kg * 16) ^ rxor;
        #pragma unroll
        for (int n = 0; n < 16; ++n) {
            const int addr = (n * 16 + r16) * 512 + cswz;
            bf16x8 wfr = *(const bf16x8*)(smem + addr);   // ds_read_b128, conflict-free
            // SWAPPED: D[j][m] -> lane holds 4 consecutive cols j of row r16
            acc[n] = __builtin_amdgcn_mfma_f32_16x16x32_bf16(wfr, a0, acc[n], 0, 0, 0);
        }
    }

    // ---------------- x_len: butterfly over K-groups; in-lane result ----------------
    ssx += __shfl_xor(ssx, 16); ssx += __shfl_xor(ssx, 32);
    const float inv = 1.0f / sqrtf(ssx);      // 1/|x_row(r16)|

    // ---------------- epilogue: LDS-transpose -> full-line sequential stores ----------------
    __syncthreads();                          // all waves done reading W; reuse as staging
    char* wbuf = smem + wave * 8192;          // 16 rows x 512 B (one 128-col half)
    const int halfsel = lane >> 5;            // 0/1
    const int l31 = lane & 31;

    #pragma unroll
    for (int h = 0; h < 2; ++h) {             // column half: cols h*128 .. h*128+127
        // stage: lane (r16, kg) writes its 8 n-windows of this half, swizzled
        #pragma unroll
        for (int n8 = 0; n8 < 8; ++n8) {
            const int n = h * 8 + n8;
            float4 wv = *(const float4*)(winv + n * 16 + kg * 4);
            float4 bv = *(const float4*)(blds + n * 16 + kg * 4);
            f32x4 o;
            o[0] = fmaxf(acc[n][0] * (inv * wv.x), EPS) + bv.x;
            o[1] = fmaxf(acc[n][1] * (inv * wv.y), EPS) + bv.y;
            o[2] = fmaxf(acc[n][2] * (inv * wv.z), EPS) + bv.z;
            o[3] = fmaxf(acc[n][3] * (inv * wv.w), EPS) + bv.w;
            const int off = r16 * 512 + ((n8 * 64 + kg * 16) ^ rxor);
            *(f32x4*)(wbuf + off) = o;        // ds_write_b128
        }
        // read back with inverse swizzle; store perfectly sequential full lines
        #pragma unroll
        for (int rp = 0; rp < 8; ++rp) {
            const int rloc = rp * 2 + halfsel;            // local row 0..15
            const int roff = (l31 * 16) ^ ((rloc & 7) << 4);
            f32x4 v = *(const f32x4*)(wbuf + rloc * 512 + roff);
            float* dst = out + (rowb + rloc) * 256 + h * 128 + l31 * 4;
            *(f32x4*)dst = v;                 // regular store: L2 merges full 128B lines
        }
        // WAR fence: next h's ds_writes must not pass this h's ds_reads
        asm volatile("s_waitcnt lgkmcnt(0)" ::: "memory");
    }
}

extern "C" void kernel_launch(void* const* d_in, const int* in_sizes, int n_in,
                              void* d_out, int out_size, void* d_ws, size_t ws_size,
                              hipStream_t stream) {
    const float* x = (const float*)d_in[0];
    const float* W = (const float*)d_in[1];
    const float* b = (const float*)d_in[2];
    float* out = (float*)d_out;

    hipFuncSetAttribute((const void*)ffn_cosnorm_kernel,
                        hipFuncAttributeMaxDynamicSharedMemorySize, LDS_BYTES);
    ffn_cosnorm_kernel<<<dim3(256), dim3(1024), LDS_BYTES, stream>>>(x, W, b, out);
}